// Round 1
// baseline (1813.033 us; speedup 1.0000x reference)
//
#include <hip/hip_runtime.h>

// Grouped GEMM: out[g*2048+b][n] = sum_k x[g*2048+b][k] * w[g][k][n]
// G=8, M_per_g=2048, K=4096, N=4096, fp32 in/out, bf16 MFMA compute.
//
// Fast path (needs 402.7 MB workspace):
//   cvt_x:  x fp32 -> bf16 [16384][4096]
//   cvt_wT: w fp32 [g][k][n] -> bf16 [g][n][k]  (transposed for k-contiguous B frags)
//   gemm_bt: m97-structure 128x128 tile, BK=32, global_load_lds(16B) staging
// Fallback (no workspace): fused-conversion GEMM, fp32 global loads -> cvt -> ds_write.

#define K_DIM 4096
#define N_DIM 4096
#define M_TOT 16384
#define GROUPS 8

typedef __bf16 bf16x8 __attribute__((ext_vector_type(8)));
typedef float f32x4 __attribute__((ext_vector_type(4)));

__device__ __forceinline__ unsigned short f2bf(float f) {
  // round-to-nearest-even fp32 -> bf16 (inputs are finite normals)
  unsigned int u = __builtin_bit_cast(unsigned int, f);
  return (unsigned short)((u + 0x7FFFu + ((u >> 16) & 1u)) >> 16);
}

#define GLOAD_LDS16(gp, lp)                                          \
  __builtin_amdgcn_global_load_lds(                                  \
      (__attribute__((address_space(1))) void*)(void*)(gp),          \
      (__attribute__((address_space(3))) void*)(void*)(lp), 16, 0, 0)

// ---------------------------------------------------------------------------
// Phase 1a: x fp32 -> bf16, 8 elements/thread, 16B stores
__global__ __launch_bounds__(256) void cvt_x_kernel(const float* __restrict__ x,
                                                    unsigned short* __restrict__ xb) {
  size_t i = (size_t)blockIdx.x * 256 + threadIdx.x;  // handles floats [8i, 8i+8)
  const float4* in = (const float4*)x;
  float4 a = in[2 * i];
  float4 b = in[2 * i + 1];
  uint4 o;
  o.x = (unsigned)f2bf(a.x) | ((unsigned)f2bf(a.y) << 16);
  o.y = (unsigned)f2bf(a.z) | ((unsigned)f2bf(a.w) << 16);
  o.z = (unsigned)f2bf(b.x) | ((unsigned)f2bf(b.y) << 16);
  o.w = (unsigned)f2bf(b.z) | ((unsigned)f2bf(b.w) << 16);
  ((uint4*)xb)[i] = o;
}

// ---------------------------------------------------------------------------
// Phase 1b: w [g][k][n] fp32 -> wt [g][n][k] bf16.  64x64 tiles via LDS (+1 pad).
__global__ __launch_bounds__(256) void cvt_wT_kernel(const float* __restrict__ w,
                                                     unsigned short* __restrict__ wt) {
  __shared__ unsigned short tile[64][65];
  const size_t base = (size_t)blockIdx.z * K_DIM * N_DIM;
  const int n0 = blockIdx.x * 64;
  const int k0 = blockIdx.y * 64;
  const int tx = threadIdx.x & 15;   // n chunk (4 floats)
  const int ty = threadIdx.x >> 4;   // k row
#pragma unroll
  for (int i = 0; i < 4; ++i) {
    int k = ty + i * 16;
    float4 v = *(const float4*)&w[base + (size_t)(k0 + k) * N_DIM + n0 + tx * 4];
    tile[k][tx * 4 + 0] = f2bf(v.x);
    tile[k][tx * 4 + 1] = f2bf(v.y);
    tile[k][tx * 4 + 2] = f2bf(v.z);
    tile[k][tx * 4 + 3] = f2bf(v.w);
  }
  __syncthreads();
  const int kx = threadIdx.x & 7;    // k chunk (8 elems -> 16B store)
  const int ny = threadIdx.x >> 3;   // n row
#pragma unroll
  for (int i = 0; i < 2; ++i) {
    int n = ny + i * 32;
    uint4 o;
    o.x = (unsigned)tile[kx * 8 + 0][n] | ((unsigned)tile[kx * 8 + 1][n] << 16);
    o.y = (unsigned)tile[kx * 8 + 2][n] | ((unsigned)tile[kx * 8 + 3][n] << 16);
    o.z = (unsigned)tile[kx * 8 + 4][n] | ((unsigned)tile[kx * 8 + 5][n] << 16);
    o.w = (unsigned)tile[kx * 8 + 6][n] | ((unsigned)tile[kx * 8 + 7][n] << 16);
    *(uint4*)&wt[base + (size_t)(n0 + n) * K_DIM + k0 + kx * 8] = o;
  }
}

// ---------------------------------------------------------------------------
// Shared MFMA inner tile: 4x4 grid of 16x16x32 per wave (64x64 wave tile)
__device__ __forceinline__ void mfma_tile(const unsigned short* sA, const unsigned short* sB,
                                          f32x4 acc[4][4], int wm, int wn, int fr, int fk) {
  bf16x8 af[4], bb[4];
#pragma unroll
  for (int t = 0; t < 4; ++t) {
    af[t] = *(const bf16x8*)&sA[(wm + t * 16 + fr) * 32 + fk];
    bb[t] = *(const bf16x8*)&sB[(wn + t * 16 + fr) * 32 + fk];
  }
#pragma unroll
  for (int i = 0; i < 4; ++i)
#pragma unroll
    for (int j = 0; j < 4; ++j)
      acc[i][j] = __builtin_amdgcn_mfma_f32_16x16x32_bf16(af[i], bb[j], acc[i][j], 0, 0, 0);
}

__device__ __forceinline__ void epilogue(float* __restrict__ C, f32x4 acc[4][4],
                                         int tm0, int tn0, int wm, int wn, int lane) {
  const int rr = (lane >> 4) * 4;  // C/D: col = lane&15, row = (lane>>4)*4 + reg
  const int cc = lane & 15;
#pragma unroll
  for (int i = 0; i < 4; ++i)
#pragma unroll
    for (int j = 0; j < 4; ++j) {
      size_t row = (size_t)(tm0 + wm + i * 16 + rr);
      size_t col = (size_t)(tn0 + wn + j * 16 + cc);
#pragma unroll
      for (int r = 0; r < 4; ++r) C[(row + r) * N_DIM + col] = acc[i][j][r];
    }
}

// ---------------------------------------------------------------------------
// Phase 2 (fast): bf16 GEMM, A=[16384][4096] bf16, BT=[g][n][k] bf16, C fp32.
__global__ __launch_bounds__(256) void gemm_bt_kernel(const unsigned short* __restrict__ A,
                                                      const unsigned short* __restrict__ BT,
                                                      float* __restrict__ C) {
  __shared__ unsigned short sA[128 * 32];
  __shared__ unsigned short sB[128 * 32];
  const int tn0 = blockIdx.x * 128;
  const int tm0 = blockIdx.y * 128;
  const int g = blockIdx.y >> 4;  // 16 row-tiles per group
  const unsigned short* Bg = BT + (size_t)g * K_DIM * N_DIM;

  const int lane = threadIdx.x & 63;
  const int wave = threadIdx.x >> 6;
  const int wm = (wave >> 1) * 64;
  const int wn = (wave & 1) * 64;

  // staging: each wave fills 16 rows x 32 cols (1024 B) per pass, 2 passes per matrix
  const int srow = wave * 16 + (lane >> 2);
  const int scol = (lane & 3) * 8;
  const unsigned short* gA0 = A + (size_t)(tm0 + srow) * K_DIM + scol;
  const unsigned short* gA1 = A + (size_t)(tm0 + 64 + srow) * K_DIM + scol;
  const unsigned short* gB0 = Bg + (size_t)(tn0 + srow) * K_DIM + scol;
  const unsigned short* gB1 = Bg + (size_t)(tn0 + 64 + srow) * K_DIM + scol;
  unsigned short* lA0 = &sA[(wave * 16) * 32];
  unsigned short* lA1 = &sA[(64 + wave * 16) * 32];
  unsigned short* lB0 = &sB[(wave * 16) * 32];
  unsigned short* lB1 = &sB[(64 + wave * 16) * 32];

  f32x4 acc[4][4];
#pragma unroll
  for (int i = 0; i < 4; ++i)
#pragma unroll
    for (int j = 0; j < 4; ++j) acc[i][j] = (f32x4){0.f, 0.f, 0.f, 0.f};

  const int fr = lane & 15;        // fragment m/n
  const int fk = (lane >> 4) * 8;  // fragment k chunk

  for (int k0 = 0; k0 < K_DIM; k0 += 32) {
    GLOAD_LDS16(gA0 + k0, lA0);
    GLOAD_LDS16(gA1 + k0, lA1);
    GLOAD_LDS16(gB0 + k0, lB0);
    GLOAD_LDS16(gB1 + k0, lB1);
    __syncthreads();  // drains vmcnt -> staging complete
    mfma_tile(sA, sB, acc, wm, wn, fr, fk);
    __syncthreads();  // LDS reads done before next overwrite
  }
  epilogue(C, acc, tm0, tn0, wm, wn, lane);
}

// ---------------------------------------------------------------------------
// Fallback: zero-workspace fused-conversion GEMM (fp32 loads -> bf16 -> ds_write)
__global__ __launch_bounds__(256) void gemm_fused_kernel(const float* __restrict__ X,
                                                         const float* __restrict__ W,
                                                         float* __restrict__ C) {
  __shared__ unsigned short sA[128 * 32];
  __shared__ unsigned short sB[128 * 32];
  const int tn0 = blockIdx.x * 128;
  const int tm0 = blockIdx.y * 128;
  const int g = blockIdx.y >> 4;
  const float* Wg = W + (size_t)g * K_DIM * N_DIM;
  const int tid = threadIdx.x;
  const int lane = tid & 63, wave = tid >> 6;
  const int wm = (wave >> 1) * 64, wn = (wave & 1) * 64;
  const int fr = lane & 15, fk = (lane >> 4) * 8;

  const int ac = (tid & 7) * 4;   // A col (4 floats)
  const int ar = tid >> 3;        // A row base 0..31
  const int bn = (tid & 31) * 4;  // B n (4 floats)
  const int bk = tid >> 5;        // B k base 0..7

  f32x4 acc[4][4];
#pragma unroll
  for (int i = 0; i < 4; ++i)
#pragma unroll
    for (int j = 0; j < 4; ++j) acc[i][j] = (f32x4){0.f, 0.f, 0.f, 0.f};

  for (int k0 = 0; k0 < K_DIM; k0 += 32) {
    float4 av[4], bv[4];
#pragma unroll
    for (int p = 0; p < 4; ++p)
      av[p] = *(const float4*)&X[(size_t)(tm0 + ar + p * 32) * K_DIM + k0 + ac];
#pragma unroll
    for (int p = 0; p < 4; ++p)
      bv[p] = *(const float4*)&Wg[(size_t)(k0 + bk + p * 8) * N_DIM + tn0 + bn];
#pragma unroll
    for (int p = 0; p < 4; ++p) {
      ushort4 s;
      s.x = f2bf(av[p].x); s.y = f2bf(av[p].y); s.z = f2bf(av[p].z); s.w = f2bf(av[p].w);
      *(ushort4*)&sA[(ar + p * 32) * 32 + ac] = s;
    }
#pragma unroll
    for (int p = 0; p < 4; ++p) {  // transposed B write: sB[n][k]
      sB[(bn + 0) * 32 + bk + p * 8] = f2bf(bv[p].x);
      sB[(bn + 1) * 32 + bk + p * 8] = f2bf(bv[p].y);
      sB[(bn + 2) * 32 + bk + p * 8] = f2bf(bv[p].z);
      sB[(bn + 3) * 32 + bk + p * 8] = f2bf(bv[p].w);
    }
    __syncthreads();
    mfma_tile(sA, sB, acc, wm, wn, fr, fk);
    __syncthreads();
  }
  epilogue(C, acc, tm0, tn0, wm, wn, lane);
}

// ---------------------------------------------------------------------------
extern "C" void kernel_launch(void* const* d_in, const int* in_sizes, int n_in,
                              void* d_out, int out_size, void* d_ws, size_t ws_size,
                              hipStream_t stream) {
  const float* x = (const float*)d_in[0];
  const float* w = (const float*)d_in[1];
  float* out = (float*)d_out;
  const size_t xe = (size_t)M_TOT * K_DIM;            // 67,108,864
  const size_t we = (size_t)GROUPS * K_DIM * N_DIM;   // 134,217,728
  const size_t need = (xe + we) * sizeof(unsigned short);  // 402.7 MB

  if (ws_size >= need) {
    unsigned short* xb = (unsigned short*)d_ws;
    unsigned short* wt = xb + xe;
    cvt_x_kernel<<<dim3((unsigned)(xe / (256 * 8))), 256, 0, stream>>>(x, xb);
    cvt_wT_kernel<<<dim3(N_DIM / 64, K_DIM / 64, GROUPS), 256, 0, stream>>>(w, wt);
    gemm_bt_kernel<<<dim3(N_DIM / 128, M_TOT / 128), 256, 0, stream>>>(xb, wt, out);
  } else {
    gemm_fused_kernel<<<dim3(N_DIM / 128, M_TOT / 128), 256, 0, stream>>>(x, w, out);
  }
}